// Round 13
// baseline (362.214 us; speedup 1.0000x reference)
//
#include <hip/hip_runtime.h>
#include <hip/hip_bf16.h>

using bf16 = __hip_bfloat16;
typedef __attribute__((ext_vector_type(8))) short bf16x8;
typedef __attribute__((ext_vector_type(4))) float f32x4;

#define DM 2048

// ---- workspace offsets (bytes) ----
#define OFF_WCZQ  0x00000000ULL  // 768x2048 bf16 (w_kv^T | w_z^T | w_dq^T)
#define OFF_WUQ   0x00300000ULL  // 2048x512 bf16
#define OFF_DOWNB 0x00500000ULL  // 4x512x512 bf16 (o_down, plain cvt)
#define OFF_WUP   0x00700000ULL  // 2048x2048 bf16 (o_up^T)
#define OFF_W2T   0x00F00000ULL  // 2048x2048 bf16 (fused down*up, transposed)
#define OFF_KC    0x01700000ULL  // 2*64*128 bf16
#define OFF_VT    0x01710000ULL  // 2*128*64 bf16 (V transposed per batch)
#define OFF_ROPE  0x01720000ULL  // 8192*32 float2
#define OFF_XB    0x01A00000ULL  // 16384x2048 bf16 (x), reused for attn-out
#define OFF_CZQ   0x05A00000ULL  // 16384x768 bf16 (c_proj | z | q_mid)
#define OFF_QF    0x07300000ULL  // 16384x2048 bf16

__device__ __forceinline__ void async16(const void* g, void* l) {
  __builtin_amdgcn_global_load_lds(
      (const __attribute__((address_space(1))) unsigned int*)g,
      (__attribute__((address_space(3))) unsigned int*)l, 16, 0, 0);
}

__device__ __forceinline__ f32x4 mfma16(bf16x8 a, bf16x8 b, f32x4 c) {
  return __builtin_amdgcn_mfma_f32_16x16x32_bf16(a, b, c, 0, 0, 0);
}

__device__ __forceinline__ float b2f(short u) {
  unsigned x = ((unsigned)(unsigned short)u) << 16;
  return __builtin_bit_cast(float, x);
}
__device__ __forceinline__ short f2bs(float f) {
  return __builtin_bit_cast(short, __float2bfloat16(f));
}

#define SB0 __builtin_amdgcn_sched_barrier(0)

__device__ __forceinline__ void cvt8(const float* __restrict__ in, bf16* __restrict__ out, size_t i) {
  float4 a = *(const float4*)(in + i);
  float4 b = *(const float4*)(in + i + 4);
  struct alignas(16) B8 { bf16 v[8]; } r;
  r.v[0] = __float2bfloat16(a.x); r.v[1] = __float2bfloat16(a.y);
  r.v[2] = __float2bfloat16(a.z); r.v[3] = __float2bfloat16(a.w);
  r.v[4] = __float2bfloat16(b.x); r.v[5] = __float2bfloat16(b.y);
  r.v[6] = __float2bfloat16(b.z); r.v[7] = __float2bfloat16(b.w);
  *(B8*)(out + i) = r;
}

// ================= flat-grid prep: 6 transposes + o_down cvt + rope + x cvt =================
__global__ __launch_bounds__(256) void prep_k(
    const float* __restrict__ w_kv, const float* __restrict__ w_z,
    const float* __restrict__ w_dq, const float* __restrict__ w_uq,
    const float* __restrict__ o_up, const float* __restrict__ o_down,
    const float* __restrict__ x,
    bf16* __restrict__ WCZQ, bf16* __restrict__ WUQ, bf16* __restrict__ WUP,
    bf16* __restrict__ DOWNB, bf16* __restrict__ XB, float2* __restrict__ ROPE) {
  __shared__ float t[32][33];
  const int b = blockIdx.x;
  if (b < 6656) {
    const float* src; bf16* dst; int K, N, tx, ty;
    if (b < 256)       { src = w_kv; dst = WCZQ;              K = 2048; N = 128;  int i = b;        tx = i % 4;  ty = i / 4;  }
    else if (b < 512)  { src = w_z;  dst = WCZQ + 128 * 2048; K = 2048; N = 128;  int i = b - 256;  tx = i % 4;  ty = i / 4;  }
    else if (b < 1536) { src = w_dq; dst = WCZQ + 256 * 2048; K = 2048; N = 512;  int i = b - 512;  tx = i % 16; ty = i / 16; }
    else if (b < 2560) { src = w_uq; dst = WUQ;               K = 512;  N = 2048; int i = b - 1536; tx = i % 64; ty = i / 64; }
    else               { src = o_up; dst = WUP;               K = 2048; N = 2048; int i = b - 2560; tx = i % 64; ty = i / 64; }
    const int tn0 = tx * 32, tk0 = ty * 32;
    const int lx = threadIdx.x & 31, ly = threadIdx.x >> 5;
#pragma unroll
    for (int p = 0; p < 4; p++) {
      int k = tk0 + ly + p * 8, n = tn0 + lx;
      if (k < K && n < N) t[ly + p * 8][lx] = src[(size_t)k * N + n];
    }
    __syncthreads();
#pragma unroll
    for (int p = 0; p < 4; p++) {
      int n = tn0 + ly + p * 8, k = tk0 + lx;
      if (n < N && k < K) dst[(size_t)n * K + k] = __float2bfloat16(t[lx][ly + p * 8]);
    }
  } else if (b < 7168) {
    cvt8(o_down, DOWNB, ((size_t)(b - 6656) * 256 + threadIdx.x) * 8);
  } else if (b < 8192) {
    int idx = (b - 7168) * 256 + threadIdx.x;  // 8192*32 entries
    int s = idx >> 5, i = idx & 31;
    double f = pow(10000.0, -((double)(2 * i)) / 64.0);
    double a = (double)s * f;
    ROPE[idx] = make_float2((float)cos(a), (float)sin(a));
  } else {
    cvt8(x, XB, ((size_t)(b - 8192) * 256 + threadIdx.x) * 8);
  }
}

// ================= 256x256 8-phase GEMM body: C = A(MxK,lda) @ Bt(NxK,ldb)^T =================
// 1024 thr / 16 waves (4Mx4N); BK=64 as 2 k-halves; LDS 128 KiB passed in.
// Counted vmcnt(2) at the 2 sync points per K-tile; max 4 outstanding/wave.
// T2 bank swizzle via pre-swizzled global source + swizzled read base.
// SYNC SKELETON = R3-stable; do not deepen (12-outstanding variants raced).
template <int OUT_BF16>
__device__ __forceinline__ void gemm8p_body(
    char* ldsb,
    const bf16* __restrict__ A, int lda,
    const bf16* __restrict__ Bt, int ldb,
    void* __restrict__ Cp, int ldc, int K, int ntiles, int wgid) {
  const int tid = threadIdx.x;
  const int lane = tid & 63, wid = tid >> 6;
  const int wr = wid >> 2, wc = wid & 3;  // 4x4 wave grid, 64x64 out per wave
  const int mt = wgid / ntiles, nt = wgid % ntiles;
  const int srow = tid >> 2;                       // 0..255
  const int sunit = (tid & 3) ^ ((tid >> 3) & 3);  // source unit pre-swizzled
  const bf16* gA = A + (size_t)(mt * 256 + srow) * lda + (sunit << 3);
  const bf16* gB = Bt + (size_t)(nt * 256 + srow) * ldb + (sunit << 3);
  char* ldsA = ldsb + tid * 16;
  char* ldsB = ldsb + 32768 + tid * 16;

#define STAGE_A(dd, h, kc) async16(gA + (kc) + (h) * 32, ldsA + (dd) * 65536 + (h) * 16384)
#define STAGE_B(dd, h, kc) async16(gB + (kc) + (h) * 32, ldsB + (dd) * 65536 + (h) * 16384)

  const int l15 = lane & 15, g = lane >> 4;
  const int gsw = g ^ ((l15 >> 1) & 3);  // swizzled read unit
  const char* ardb = ldsb + (size_t)(wr * 64 + l15) * 64 + (gsw << 4);
  const char* brdb = ldsb + 32768 + (size_t)(wc * 64 + l15) * 64 + (gsw << 4);

  f32x4 acc[4][4] = {};
  // prologue: stage K-tile 0 (FIFO: A-h0, B-h0, A-h1, B-h1 = 4 loads)
  STAGE_A(0, 0, 0); STAGE_B(0, 0, 0); STAGE_A(0, 1, 0); STAGE_B(0, 1, 0);

  const int nkt = K >> 6;
  for (int t = 0; t < nkt; ++t) {
    const int d = t & 1;
    const char* aB = ardb + d * 65536;
    const char* bB = brdb + d * 65536;
    const int kn = (t + 1) << 6;
    const bool pf = (t + 1) < nkt;
    bf16x8 a[4], b0, b1;
    // ---- P1: sync (A-h0,B-h0 landed), stage A-h0', compute (h0, n0/n1) ----
    SB0;
    asm volatile("s_waitcnt vmcnt(2)" ::: "memory");
    __builtin_amdgcn_s_barrier();
    asm volatile("" ::: "memory");
    SB0;
    if (pf) STAGE_A(d ^ 1, 0, kn);
#pragma unroll
    for (int m = 0; m < 4; m++) a[m] = *(const bf16x8*)(aB + m * 1024);
    b0 = *(const bf16x8*)(bB);
    b1 = *(const bf16x8*)(bB + 1024);
    __builtin_amdgcn_s_setprio(1);
#pragma unroll
    for (int m = 0; m < 4; m++) {
      acc[m][0] = mfma16(a[m], b0, acc[m][0]);
      acc[m][1] = mfma16(a[m], b1, acc[m][1]);
    }
    __builtin_amdgcn_s_setprio(0);
    // ---- P2: stage B-h0', compute (h0, n2/n3) ----
    if (pf) STAGE_B(d ^ 1, 0, kn);
    b0 = *(const bf16x8*)(bB + 2048);
    b1 = *(const bf16x8*)(bB + 3072);
    __builtin_amdgcn_s_setprio(1);
#pragma unroll
    for (int m = 0; m < 4; m++) {
      acc[m][2] = mfma16(a[m], b0, acc[m][2]);
      acc[m][3] = mfma16(a[m], b1, acc[m][3]);
    }
    __builtin_amdgcn_s_setprio(0);
    // ---- P3: sync (A-h1,B-h1 landed), stage A-h1', compute (h1, n0/n1) ----
    SB0;
    if (pf) asm volatile("s_waitcnt vmcnt(2)" ::: "memory");
    else    asm volatile("s_waitcnt vmcnt(0)" ::: "memory");
    __builtin_amdgcn_s_barrier();
    asm volatile("" ::: "memory");
    SB0;
    if (pf) STAGE_A(d ^ 1, 1, kn);
#pragma unroll
    for (int m = 0; m < 4; m++) a[m] = *(const bf16x8*)(aB + 16384 + m * 1024);
    b0 = *(const bf16x8*)(bB + 16384);
    b1 = *(const bf16x8*)(bB + 16384 + 1024);
    __builtin_amdgcn_s_setprio(1);
#pragma unroll
    for (int m = 0; m < 4; m++) {
      acc[m][0] = mfma16(a[m], b0, acc[m][0]);
      acc[m][1] = mfma16(a[m], b1, acc[m][1]);
    }
    __builtin_amdgcn_s_setprio(0);
    // ---- P4: stage B-h1', compute (h1, n2/n3) ----
    if (pf) STAGE_B(d ^ 1, 1, kn);
    b0 = *(const bf16x8*)(bB + 16384 + 2048);
    b1 = *(const bf16x8*)(bB + 16384 + 3072);
    __builtin_amdgcn_s_setprio(1);
#pragma unroll
    for (int m = 0; m < 4; m++) {
      acc[m][2] = mfma16(a[m], b0, acc[m][2]);
      acc[m][3] = mfma16(a[m], b1, acc[m][3]);
    }
    __builtin_amdgcn_s_setprio(0);
  }
#undef STAGE_A
#undef STAGE_B

  const int r4 = (lane >> 4) << 2;
  const size_t row0 = (size_t)mt * 256 + wr * 64;
  const int col0 = nt * 256 + wc * 64;
#pragma unroll
  for (int m = 0; m < 4; m++)
#pragma unroll
    for (int n = 0; n < 4; n++)
#pragma unroll
      for (int j = 0; j < 4; j++) {
        size_t row = row0 + m * 16 + r4 + j;
        size_t col = (size_t)col0 + n * 16 + l15;
        if (OUT_BF16) ((bf16*)Cp)[row * ldc + col] = __float2bfloat16(acc[m][n][j]);
        else          ((float*)Cp)[row * ldc + col] = acc[m][n][j];
      }
}

template <int OUT_BF16>
__global__ __launch_bounds__(1024, 1) void gemm8p(
    const bf16* __restrict__ A, int lda,
    const bf16* __restrict__ Bt, int ldb,
    void* __restrict__ Cp, int ldc, int K, int ntiles) {
  __shared__ __align__(16) char lds[131072];
  const int wgid = (blockIdx.x & 7) * (gridDim.x >> 3) + (blockIdx.x >> 3);
  gemm8p_body<OUT_BF16>(lds, A, lda, Bt, ldb, Cp, ldc, K, ntiles, wgid);
}

// ---------------- combined launch: czq GEMM (0..191) + inline compress (nt==0 blocks) + W2T (192..255) ----------------
// czq tile (mt, nt=0) covers rows mt*256..+255, cols 0..255 = exactly the data for token-blocks
// 2mt and 2mt+1 of the compression -> run compress inline after draining this block's own C-writes.
__global__ __launch_bounds__(1024, 1) void czq_w2t_k(
    const bf16* __restrict__ XB, const bf16* __restrict__ WCZQ, bf16* __restrict__ CZQ,
    const bf16* __restrict__ WUP, const bf16* __restrict__ DOWNB, bf16* __restrict__ W2T,
    const float* __restrict__ b_comp, const float* __restrict__ kv_g,
    const float* __restrict__ kv_b, bf16* __restrict__ KC, bf16* __restrict__ VT) {
  __shared__ __align__(16) char lds[131072];
  const int bx = blockIdx.x;
  if (bx < 192) {
    const int wgid = (bx & 7) * 24 + (bx >> 3);  // bijective: 192 % 8 == 0
    gemm8p_body<1>(lds, XB, DM, WCZQ, DM, CZQ, 768, DM, 3, wgid);
    const int mt = wgid / 3, nt = wgid % 3;
    if (nt == 0) {
      // drain this block's C stores; L1 is write-through/invalidated on store, L2 has the data
      asm volatile("s_waitcnt vmcnt(0)" ::: "memory");
      __syncthreads();
      float* sm = (float*)lds;  // [2][1152] floats: sn[4][128] | sd[4][128] | sv[128]
      const int t = threadIdx.x;
      const int local = t >> 9;       // which of the 2 token-blocks
      const int tt = t & 511;
      const int c = tt & 127, qtr = tt >> 7;
      const int blk = 2 * mt + local;
      const size_t t0 = (size_t)blk * 128;
      float num = 0.f, den = 0.f;
      for (int m = qtr * 32; m < qtr * 32 + 32; m++) {
        const bf16* r = CZQ + (t0 + m) * 768;
        float w = expf(__bfloat162float(r[128 + c]) + b_comp[m * 128 + c]);
        den += w;
        num += w * __bfloat162float(r[c]);
      }
      float* sn = sm + local * 1152;
      float* sd = sm + local * 1152 + 512;
      float* sv = sm + local * 1152 + 1024;
      sn[qtr * 128 + c] = num;
      sd[qtr * 128 + c] = den;
      __syncthreads();
      if (qtr == 0)
        sv[c] = (sn[c] + sn[128 + c] + sn[256 + c] + sn[384 + c]) /
                (sd[c] + sd[128 + c] + sd[256 + c] + sd[384 + c]);
      __syncthreads();
      if (qtr == 0) {
        float v = sv[c];
        float mu = 0.f;
        for (int i = 0; i < 128; i++) mu += sv[i];
        mu *= (1.f / 128.f);
        float var = 0.f;
        for (int i = 0; i < 128; i++) { float d = sv[i] - mu; var += d * d; }
        var *= (1.f / 128.f);
        float kc = (v - mu) * rsqrtf(var + 1e-6f) * kv_g[c] + kv_b[c];
        const int bb = blk >> 6, kb = blk & 63;
        KC[(size_t)blk * 128 + c] = __float2bfloat16(kc);
        VT[(size_t)bb * 8192 + c * 64 + kb] = __float2bfloat16(v);
      }
    }
  } else {
    const int b2 = bx - 192;
    const int grp = b2 >> 4, inner = b2 & 15;
    const int wgid = (inner & 7) * 2 + (inner >> 3);
    gemm8p_body<1>(lds, WUP + grp * 512, DM, DOWNB + (size_t)grp * 512 * 512, 512,
                   W2T + grp * 512, DM, 512, 2, wgid);
  }
}

// ---------------- attention: fused q-LN+RoPE, K/V^T direct from global, swizzled LDS ----------------
__global__ __launch_bounds__(256) void attn_k(
    const bf16* __restrict__ qln, const bf16* __restrict__ kc,
    const bf16* __restrict__ vt, const float* __restrict__ sink_logits,
    const float* __restrict__ gamma, const float* __restrict__ beta,
    const float2* __restrict__ rope, bf16* __restrict__ out) {
  __shared__ bf16 Qs[128 * 128];  // swizzled rows; P[128][64] overlays after QK^T
  const int qt = blockIdx.x, hh = blockIdx.y, b = blockIdx.z;
  const int nk = qt + 1;
  const int ntk = (nk + 15) >> 4;
  const int nkk = (nk + 31) >> 5;
  const int tid = threadIdx.x, wave = tid >> 6, lane = tid & 63;
  const int l15 = lane & 15, g = lane >> 4;
  const size_t t0 = (size_t)b * 8192 + (size_t)qt * 128;
  const bf16* kbase = kc + (size_t)b * 64 * 128;
  const bf16* vbase = vt + (size_t)b * 128 * 64;

  {
    const int q = tid >> 1, hf = tid & 1;
    const bf16* gq = qln + (t0 + q) * 2048 + hh * 128 + hf * 64;
    bf16x8 r[8];
#pragma unroll
    for (int i = 0; i < 8; i++) r[i] = *(const bf16x8*)(gq + i * 8);
    float sum = 0.f;
#pragma unroll
    for (int i = 0; i < 8; i++)
#pragma unroll
      for (int j = 0; j < 8; j++) sum += b2f(r[i][j]);
    sum += __shfl_xor(sum, 1);
    const float mu = sum * (1.f / 128.f);
    float var = 0.f;
#pragma unroll
    for (int i = 0; i < 8; i++)
#pragma unroll
      for (int j = 0; j < 8; j++) { float d = b2f(r[i][j]) - mu; var += d * d; }
    var += __shfl_xor(var, 1);
    const float inv = rsqrtf(var * (1.f / 128.f) + 1e-6f);
    const int c0 = hf * 64;
#pragma unroll
    for (int i = 0; i < 8; i++) {
      float y[8];
#pragma unroll
      for (int j = 0; j < 8; j++) {
        int ch = c0 + i * 8 + j;
        y[j] = (b2f(r[i][j]) - mu) * inv * gamma[ch] + beta[ch];
      }
      if (hf) {
#pragma unroll
        for (int j = 0; j < 8; j += 2) {
          float2 cs = rope[((size_t)qt * 128 + q) * 32 + i * 4 + (j >> 1)];
          float e = y[j], o = y[j + 1];
          y[j] = e * cs.x - o * cs.y;
          y[j + 1] = e * cs.y + o * cs.x;
        }
      }
      bf16x8 w;
#pragma unroll
      for (int j = 0; j < 8; j++) w[j] = f2bs(y[j]);
      *(bf16x8*)(Qs + q * 128 + ((hf * 8 + (i ^ (q & 7))) << 3)) = w;
    }
  }
  __syncthreads();

  bf16x8 af[2][4];
#pragma unroll
  for (int m = 0; m < 2; m++) {
    const int q = wave * 32 + m * 16 + l15;
#pragma unroll
    for (int kk = 0; kk < 4; kk++) {
      const int u = (kk * 4 + g) ^ (q & 7);
      af[m][kk] = *(const bf16x8*)(Qs + q * 128 + u * 8);
    }
  }
  __syncthreads();  // Qs dead; safe to overlay P

  f32x4 sacc[2][4] = {};
#pragma unroll
  for (int n = 0; n < 4; n++) {
    if (n < ntk) {
      const bf16* kr = kbase + (n * 16 + l15) * 128 + g * 8;
      bf16x8 b0 = *(const bf16x8*)(kr);
      bf16x8 b1 = *(const bf16x8*)(kr + 32);
      bf16x8 b2 = *(const bf16x8*)(kr + 64);
      bf16x8 b3 = *(const bf16x8*)(kr + 96);
      __builtin_amdgcn_s_setprio(1);
      sacc[0][n] = mfma16(af[0][0], b0, sacc[0][n]);
      sacc[1][n] = mfma16(af[1][0], b0, sacc[1][n]);
      sacc[0][n] = mfma16(af[0][1], b1, sacc[0][n]);
      sacc[1][n] = mfma16(af[1][1], b1, sacc[1][n]);
      sacc[0][n] = mfma16(af[0][2], b2, sacc[0][n]);
      sacc[1][n] = mfma16(af[1][2], b2, sacc[1][n]);
      sacc[0][n] = mfma16(af[0][3], b3, sacc[0][n]);
      sacc[1][n] = mfma16(af[1][3], b3, sacc[1][n]);
      __builtin_amdgcn_s_setprio(0);
    }
  }

  const float sink = expf(sink_logits[hh]);
  const float scale = 0.088388347648318447f;  // 1/sqrt(128)
  bf16* P = Qs;
#pragma unroll
  for (int m = 0; m < 2; m++) {
    float pv[4][4];
    float rs[4] = {0.f, 0.f, 0.f, 0.f};
#pragma unroll
    for (int n = 0; n < 4; n++) {
      int key = n * 16 + l15;
#pragma unroll
      for (int j = 0; j < 4; j++) {
        float p = (key < nk) ? expf(sacc[m][n][j] * scale) : 0.f;
        pv[n][j] = p;
        rs[j] += p;
      }
    }
#pragma unroll
    for (int j = 0; j < 4; j++) {
      float v = rs[j];
      v += __shfl_xor(v, 1); v += __shfl_xor(v, 2);
      v += __shfl_xor(v, 4); v += __shfl_xor(v, 8);
      rs[j] = 1.0f / (v + sink);
    }
    const int row0 = wave * 32 + m * 16 + (g << 2);
#pragma unroll
    for (int n = 0; n < 4; n++)
#pragma unroll
      for (int j = 0; j < 4; j++) {
        int q = row0 + j;
        int k = n * 16 + l15;
        P[q * 64 + ((((k >> 3) ^ (q & 7)) << 3) | (k & 7))] =
            __float2bfloat16(pv[n][j] * rs[j]);
      }
  }
  // no barrier: PV reads only this wave's own P rows

  f32x4 oacc[2][8] = {};
#pragma unroll
  for (int kk = 0; kk < 2; kk++) {
    if (kk < nkk) {
      bf16x8 pa[2];
#pragma unroll
      for (int m = 0; m < 2; m++) {
        const int q = wave * 32 + m * 16 + l15;
        const int u = (kk * 4 + g) ^ (q & 7);
        pa[m] = *(const bf16x8*)(P + q * 64 + u * 8);
      }
#pragma unroll
      for (int n = 0; n < 8; n++) {
        bf16x8 vb = *(const bf16x8*)(vbase + (n * 16 + l15) * 64 + kk * 32 + g * 8);
        __builtin_amdgcn_s_setprio(1);
        oacc[0][n] = mfma16(pa[0], vb, oacc[0][n]);
        oacc[1][n] = mfma16(pa[1], vb, oacc[1][n]);
        __builtin_amdgcn_s_setprio(0);
      }
    }
  }

  bf16* ob = out + t0 * 2048 + hh * 128;
  const int r4 = g << 2;
#pragma unroll
  for (int m = 0; m < 2; m++)
#pragma unroll
    for (int n = 0; n < 8; n++)
#pragma unroll
      for (int j = 0; j < 4; j++)
        ob[(size_t)(wave * 32 + m * 16 + r4 + j) * 2048 + n * 16 + l15] =
            __float2bfloat16(oacc[m][n][j]);
}

extern "C" void kernel_launch(void* const* d_in, const int* in_sizes, int n_in,
                              void* d_out, int out_size, void* d_ws, size_t ws_size,
                              hipStream_t stream) {
  const float* x      = (const float*)d_in[0];
  const float* w_kv   = (const float*)d_in[1];
  const float* w_z    = (const float*)d_in[2];
  const float* b_comp = (const float*)d_in[3];
  const float* w_dq   = (const float*)d_in[4];
  const float* w_uq   = (const float*)d_in[5];
  const float* o_down = (const float*)d_in[6];
  const float* o_up   = (const float*)d_in[7];
  const float* kv_g   = (const float*)d_in[8];
  const float* kv_b   = (const float*)d_in[9];
  const float* q_g    = (const float*)d_in[10];
  const float* q_b    = (const float*)d_in[11];
  const float* sinkl  = (const float*)d_in[12];
  char* ws = (char*)d_ws;
  bf16*   WCZQ  = (bf16*)(ws + OFF_WCZQ);
  bf16*   WUQ   = (bf16*)(ws + OFF_WUQ);
  bf16*   DOWNB = (bf16*)(ws + OFF_DOWNB);
  bf16*   WUP   = (bf16*)(ws + OFF_WUP);
  bf16*   W2T   = (bf16*)(ws + OFF_W2T);
  bf16*   KC    = (bf16*)(ws + OFF_KC);
  bf16*   VT    = (bf16*)(ws + OFF_VT);
  float2* ROPE  = (float2*)(ws + OFF_ROPE);
  bf16*   XB    = (bf16*)(ws + OFF_XB);
  bf16*   CZQ   = (bf16*)(ws + OFF_CZQ);
  bf16*   QF    = (bf16*)(ws + OFF_QF);
  bf16*   ATT   = (bf16*)(ws + OFF_XB);
  float*  OUT   = (float*)d_out;

  // all weight prep + converts + rope table in one launch
  prep_k<<<24576, 256, 0, stream>>>(w_kv, w_z, w_dq, w_uq, o_up, o_down, x,
                                    WCZQ, WUQ, WUP, DOWNB, XB, ROPE);
  // czq GEMM + inline compression/kv-LN + W2T group GEMMs, one full-machine launch
  czq_w2t_k<<<256, 1024, 0, stream>>>(XB, WCZQ, CZQ, WUP, DOWNB, W2T,
                                      b_comp, kv_g, kv_b, KC, VT);
  // q = q_mid @ w_uq   (16384 x 2048, K=512)
  gemm8p<1><<<512, 1024, 0, stream>>>(CZQ + 256, 768, WUQ, 512, QF, DM, 512, 8);
  // attention (fused q-LN + rope)
  attn_k<<<dim3(64, 16, 2), 256, 0, stream>>>(QF, KC, VT, sinkl, q_g, q_b, ROPE, ATT);
  // final: OUT = ATT @ W2T^T  (16384 x 2048, K=2048)
  gemm8p<0><<<512, 1024, 0, stream>>>(ATT, DM, W2T, DM, OUT, DM, DM, 8);
}

// Round 14
// 338.145 us; speedup vs baseline: 1.0712x; 1.0712x over previous
//
#include <hip/hip_runtime.h>
#include <hip/hip_bf16.h>

using bf16 = __hip_bfloat16;
typedef __attribute__((ext_vector_type(8))) short bf16x8;
typedef __attribute__((ext_vector_type(4))) float f32x4;

#define DM 2048

// ---- workspace offsets (bytes) ----
#define OFF_WCZQ  0x00000000ULL  // 768x2048 bf16 (w_kv^T | w_z^T | w_dq^T)
#define OFF_WUQ   0x00300000ULL  // 2048x512 bf16
#define OFF_DOWNB 0x00500000ULL  // 4x512x512 bf16 (o_down, plain cvt)
#define OFF_WUP   0x00700000ULL  // 2048x2048 bf16 (o_up^T)
#define OFF_W2T   0x00F00000ULL  // 2048x2048 bf16 (fused down*up, transposed)
#define OFF_KC    0x01700000ULL  // 2*64*128 bf16
#define OFF_VT    0x01710000ULL  // 2*128*64 bf16 (V transposed per batch)
#define OFF_ROPE  0x01720000ULL  // 8192*32 float2
#define OFF_XB    0x01A00000ULL  // 16384x2048 bf16 (x), reused for attn-out
#define OFF_CZQ   0x05A00000ULL  // 16384x768 bf16 (c_proj | z | q_mid)

__device__ __forceinline__ void async16(const void* g, void* l) {
  __builtin_amdgcn_global_load_lds(
      (const __attribute__((address_space(1))) unsigned int*)g,
      (__attribute__((address_space(3))) unsigned int*)l, 16, 0, 0);
}

__device__ __forceinline__ f32x4 mfma16(bf16x8 a, bf16x8 b, f32x4 c) {
  return __builtin_amdgcn_mfma_f32_16x16x32_bf16(a, b, c, 0, 0, 0);
}

__device__ __forceinline__ float b2f(short u) {
  unsigned x = ((unsigned)(unsigned short)u) << 16;
  return __builtin_bit_cast(float, x);
}
__device__ __forceinline__ short f2bs(float f) {
  return __builtin_bit_cast(short, __float2bfloat16(f));
}

#define SB0 __builtin_amdgcn_sched_barrier(0)

__device__ __forceinline__ void cvt8(const float* __restrict__ in, bf16* __restrict__ out, size_t i) {
  float4 a = *(const float4*)(in + i);
  float4 b = *(const float4*)(in + i + 4);
  struct alignas(16) B8 { bf16 v[8]; } r;
  r.v[0] = __float2bfloat16(a.x); r.v[1] = __float2bfloat16(a.y);
  r.v[2] = __float2bfloat16(a.z); r.v[3] = __float2bfloat16(a.w);
  r.v[4] = __float2bfloat16(b.x); r.v[5] = __float2bfloat16(b.y);
  r.v[6] = __float2bfloat16(b.z); r.v[7] = __float2bfloat16(b.w);
  *(B8*)(out + i) = r;
}

// ================= flat-grid prep: 6 transposes + o_down cvt + rope + x cvt =================
__global__ __launch_bounds__(256) void prep_k(
    const float* __restrict__ w_kv, const float* __restrict__ w_z,
    const float* __restrict__ w_dq, const float* __restrict__ w_uq,
    const float* __restrict__ o_up, const float* __restrict__ o_down,
    const float* __restrict__ x,
    bf16* __restrict__ WCZQ, bf16* __restrict__ WUQ, bf16* __restrict__ WUP,
    bf16* __restrict__ DOWNB, bf16* __restrict__ XB, float2* __restrict__ ROPE) {
  __shared__ float t[32][33];
  const int b = blockIdx.x;
  if (b < 6656) {
    const float* src; bf16* dst; int K, N, tx, ty;
    if (b < 256)       { src = w_kv; dst = WCZQ;              K = 2048; N = 128;  int i = b;        tx = i % 4;  ty = i / 4;  }
    else if (b < 512)  { src = w_z;  dst = WCZQ + 128 * 2048; K = 2048; N = 128;  int i = b - 256;  tx = i % 4;  ty = i / 4;  }
    else if (b < 1536) { src = w_dq; dst = WCZQ + 256 * 2048; K = 2048; N = 512;  int i = b - 512;  tx = i % 16; ty = i / 16; }
    else if (b < 2560) { src = w_uq; dst = WUQ;               K = 512;  N = 2048; int i = b - 1536; tx = i % 64; ty = i / 64; }
    else               { src = o_up; dst = WUP;               K = 2048; N = 2048; int i = b - 2560; tx = i % 64; ty = i / 64; }
    const int tn0 = tx * 32, tk0 = ty * 32;
    const int lx = threadIdx.x & 31, ly = threadIdx.x >> 5;
#pragma unroll
    for (int p = 0; p < 4; p++) {
      int k = tk0 + ly + p * 8, n = tn0 + lx;
      if (k < K && n < N) t[ly + p * 8][lx] = src[(size_t)k * N + n];
    }
    __syncthreads();
#pragma unroll
    for (int p = 0; p < 4; p++) {
      int n = tn0 + ly + p * 8, k = tk0 + lx;
      if (n < N && k < K) dst[(size_t)n * K + k] = __float2bfloat16(t[lx][ly + p * 8]);
    }
  } else if (b < 7168) {
    cvt8(o_down, DOWNB, ((size_t)(b - 6656) * 256 + threadIdx.x) * 8);
  } else if (b < 8192) {
    int idx = (b - 7168) * 256 + threadIdx.x;  // 8192*32 entries
    int s = idx >> 5, i = idx & 31;
    double f = pow(10000.0, -((double)(2 * i)) / 64.0);
    double a = (double)s * f;
    ROPE[idx] = make_float2((float)cos(a), (float)sin(a));
  } else {
    cvt8(x, XB, ((size_t)(b - 8192) * 256 + threadIdx.x) * 8);
  }
}

// ================= 256x256 8-phase GEMM body: C = A(MxK,lda) @ Bt(NxK,ldb)^T =================
// 1024 thr / 16 waves (4Mx4N); BK=64 as 2 k-halves; LDS 128 KiB passed in.
// Counted vmcnt(2) at the 2 sync points per K-tile; max 4 outstanding/wave.
// OUT mode: 0 = f32 global, 1 = bf16 global, 2 = bf16 plain into LDS ([4][128][128], sub-tiles)
// SYNC SKELETON = R3-stable; do not deepen (12-outstanding variants raced).
template <int OUT_MODE>
__device__ __forceinline__ void gemm8p_body(
    char* ldsb,
    const bf16* __restrict__ A, int lda,
    const bf16* __restrict__ Bt, int ldb,
    void* __restrict__ Cp, int ldc, int K, int ntiles, int wgid) {
  const int tid = threadIdx.x;
  const int lane = tid & 63, wid = tid >> 6;
  const int wr = wid >> 2, wc = wid & 3;  // 4x4 wave grid, 64x64 out per wave
  const int mt = wgid / ntiles, nt = wgid % ntiles;
  const int srow = tid >> 2;                       // 0..255
  const int sunit = (tid & 3) ^ ((tid >> 3) & 3);  // source unit pre-swizzled
  const bf16* gA = A + (size_t)(mt * 256 + srow) * lda + (sunit << 3);
  const bf16* gB = Bt + (size_t)(nt * 256 + srow) * ldb + (sunit << 3);
  char* ldsA = ldsb + tid * 16;
  char* ldsB = ldsb + 32768 + tid * 16;

#define STAGE_A(dd, h, kc) async16(gA + (kc) + (h) * 32, ldsA + (dd) * 65536 + (h) * 16384)
#define STAGE_B(dd, h, kc) async16(gB + (kc) + (h) * 32, ldsB + (dd) * 65536 + (h) * 16384)

  const int l15 = lane & 15, g = lane >> 4;
  const int gsw = g ^ ((l15 >> 1) & 3);  // swizzled read unit
  const char* ardb = ldsb + (size_t)(wr * 64 + l15) * 64 + (gsw << 4);
  const char* brdb = ldsb + 32768 + (size_t)(wc * 64 + l15) * 64 + (gsw << 4);

  f32x4 acc[4][4] = {};
  // prologue: stage K-tile 0 (FIFO: A-h0, B-h0, A-h1, B-h1 = 4 loads)
  STAGE_A(0, 0, 0); STAGE_B(0, 0, 0); STAGE_A(0, 1, 0); STAGE_B(0, 1, 0);

  const int nkt = K >> 6;
  for (int t = 0; t < nkt; ++t) {
    const int d = t & 1;
    const char* aB = ardb + d * 65536;
    const char* bB = brdb + d * 65536;
    const int kn = (t + 1) << 6;
    const bool pf = (t + 1) < nkt;
    bf16x8 a[4], b0, b1;
    // ---- P1: sync (A-h0,B-h0 landed), stage A-h0', compute (h0, n0/n1) ----
    SB0;
    asm volatile("s_waitcnt vmcnt(2)" ::: "memory");
    __builtin_amdgcn_s_barrier();
    asm volatile("" ::: "memory");
    SB0;
    if (pf) STAGE_A(d ^ 1, 0, kn);
#pragma unroll
    for (int m = 0; m < 4; m++) a[m] = *(const bf16x8*)(aB + m * 1024);
    b0 = *(const bf16x8*)(bB);
    b1 = *(const bf16x8*)(bB + 1024);
    __builtin_amdgcn_s_setprio(1);
#pragma unroll
    for (int m = 0; m < 4; m++) {
      acc[m][0] = mfma16(a[m], b0, acc[m][0]);
      acc[m][1] = mfma16(a[m], b1, acc[m][1]);
    }
    __builtin_amdgcn_s_setprio(0);
    // ---- P2: stage B-h0', compute (h0, n2/n3) ----
    if (pf) STAGE_B(d ^ 1, 0, kn);
    b0 = *(const bf16x8*)(bB + 2048);
    b1 = *(const bf16x8*)(bB + 3072);
    __builtin_amdgcn_s_setprio(1);
#pragma unroll
    for (int m = 0; m < 4; m++) {
      acc[m][2] = mfma16(a[m], b0, acc[m][2]);
      acc[m][3] = mfma16(a[m], b1, acc[m][3]);
    }
    __builtin_amdgcn_s_setprio(0);
    // ---- P3: sync (A-h1,B-h1 landed), stage A-h1', compute (h1, n0/n1) ----
    SB0;
    if (pf) asm volatile("s_waitcnt vmcnt(2)" ::: "memory");
    else    asm volatile("s_waitcnt vmcnt(0)" ::: "memory");
    __builtin_amdgcn_s_barrier();
    asm volatile("" ::: "memory");
    SB0;
    if (pf) STAGE_A(d ^ 1, 1, kn);
#pragma unroll
    for (int m = 0; m < 4; m++) a[m] = *(const bf16x8*)(aB + 16384 + m * 1024);
    b0 = *(const bf16x8*)(bB + 16384);
    b1 = *(const bf16x8*)(bB + 16384 + 1024);
    __builtin_amdgcn_s_setprio(1);
#pragma unroll
    for (int m = 0; m < 4; m++) {
      acc[m][0] = mfma16(a[m], b0, acc[m][0]);
      acc[m][1] = mfma16(a[m], b1, acc[m][1]);
    }
    __builtin_amdgcn_s_setprio(0);
    // ---- P4: stage B-h1', compute (h1, n2/n3) ----
    if (pf) STAGE_B(d ^ 1, 1, kn);
    b0 = *(const bf16x8*)(bB + 16384 + 2048);
    b1 = *(const bf16x8*)(bB + 16384 + 3072);
    __builtin_amdgcn_s_setprio(1);
#pragma unroll
    for (int m = 0; m < 4; m++) {
      acc[m][2] = mfma16(a[m], b0, acc[m][2]);
      acc[m][3] = mfma16(a[m], b1, acc[m][3]);
    }
    __builtin_amdgcn_s_setprio(0);
  }
#undef STAGE_A
#undef STAGE_B

  const int r4 = (lane >> 4) << 2;
  if (OUT_MODE == 2) {
    __syncthreads();  // all waves done reading GEMM LDS before overwrite
    bf16* q16 = (bf16*)ldsb;
#pragma unroll
    for (int m = 0; m < 4; m++)
#pragma unroll
      for (int n = 0; n < 4; n++)
#pragma unroll
        for (int j = 0; j < 4; j++) {
          int rl = wr * 64 + m * 16 + r4 + j;
          int cl = wc * 64 + n * 16 + l15;
          int s = ((rl >> 7) << 1) | (cl >> 7);
          q16[s * 16384 + (rl & 127) * 128 + (cl & 127)] = __float2bfloat16(acc[m][n][j]);
        }
  } else {
    const size_t row0 = (size_t)mt * 256 + wr * 64;
    const int col0 = nt * 256 + wc * 64;
#pragma unroll
    for (int m = 0; m < 4; m++)
#pragma unroll
      for (int n = 0; n < 4; n++)
#pragma unroll
        for (int j = 0; j < 4; j++) {
          size_t row = row0 + m * 16 + r4 + j;
          size_t col = (size_t)col0 + n * 16 + l15;
          if (OUT_MODE == 1) ((bf16*)Cp)[row * ldc + col] = __float2bfloat16(acc[m][n][j]);
          else               ((float*)Cp)[row * ldc + col] = acc[m][n][j];
        }
  }
}

template <int OUT_MODE>
__global__ __launch_bounds__(1024, 1) void gemm8p(
    const bf16* __restrict__ A, int lda,
    const bf16* __restrict__ Bt, int ldb,
    void* __restrict__ Cp, int ldc, int K, int ntiles) {
  __shared__ __align__(16) char lds[131072];
  const int wgid = (blockIdx.x & 7) * (gridDim.x >> 3) + (blockIdx.x >> 3);
  gemm8p_body<OUT_MODE>(lds, A, lda, Bt, ldb, Cp, ldc, K, ntiles, wgid);
}

// ---------------- combined launch: czq GEMM (0..191) + inline compress (nt==0 blocks) + W2T (192..255) ----------------
__global__ __launch_bounds__(1024, 1) void czq_w2t_k(
    const bf16* __restrict__ XB, const bf16* __restrict__ WCZQ, bf16* __restrict__ CZQ,
    const bf16* __restrict__ WUP, const bf16* __restrict__ DOWNB, bf16* __restrict__ W2T,
    const float* __restrict__ b_comp, const float* __restrict__ kv_g,
    const float* __restrict__ kv_b, bf16* __restrict__ KC, bf16* __restrict__ VT) {
  __shared__ __align__(16) char lds[131072];
  const int bx = blockIdx.x;
  if (bx < 192) {
    const int wgid = (bx & 7) * 24 + (bx >> 3);  // bijective: 192 % 8 == 0
    gemm8p_body<1>(lds, XB, DM, WCZQ, DM, CZQ, 768, DM, 3, wgid);
    const int mt = wgid / 3, nt = wgid % 3;
    if (nt == 0) {
      asm volatile("s_waitcnt vmcnt(0)" ::: "memory");
      __syncthreads();
      float* sm = (float*)lds;  // [2][1152] floats: sn[4][128] | sd[4][128] | sv[128]
      const int t = threadIdx.x;
      const int local = t >> 9;
      const int tt = t & 511;
      const int c = tt & 127, qtr = tt >> 7;
      const int blk = 2 * mt + local;
      const size_t t0 = (size_t)blk * 128;
      float num = 0.f, den = 0.f;
      for (int m = qtr * 32; m < qtr * 32 + 32; m++) {
        const bf16* r = CZQ + (t0 + m) * 768;
        float w = expf(__bfloat162float(r[128 + c]) + b_comp[m * 128 + c]);
        den += w;
        num += w * __bfloat162float(r[c]);
      }
      float* sn = sm + local * 1152;
      float* sd = sm + local * 1152 + 512;
      float* sv = sm + local * 1152 + 1024;
      sn[qtr * 128 + c] = num;
      sd[qtr * 128 + c] = den;
      __syncthreads();
      if (qtr == 0)
        sv[c] = (sn[c] + sn[128 + c] + sn[256 + c] + sn[384 + c]) /
                (sd[c] + sd[128 + c] + sd[256 + c] + sd[384 + c]);
      __syncthreads();
      if (qtr == 0) {
        float v = sv[c];
        float mu = 0.f;
        for (int i = 0; i < 128; i++) mu += sv[i];
        mu *= (1.f / 128.f);
        float var = 0.f;
        for (int i = 0; i < 128; i++) { float d = sv[i] - mu; var += d * d; }
        var *= (1.f / 128.f);
        float kc = (v - mu) * rsqrtf(var + 1e-6f) * kv_g[c] + kv_b[c];
        const int bb = blk >> 6, kb = blk & 63;
        KC[(size_t)blk * 128 + c] = __float2bfloat16(kc);
        VT[(size_t)bb * 8192 + c * 64 + kb] = __float2bfloat16(v);
      }
    }
  } else {
    const int b2 = bx - 192;
    const int grp = b2 >> 4, inner = b2 & 15;
    const int wgid = (inner & 7) * 2 + (inner >> 3);
    gemm8p_body<1>(lds, WUP + grp * 512, DM, DOWNB + (size_t)grp * 512 * 512, 512,
                   W2T + grp * 512, DM, 512, 2, wgid);
  }
}

// ---------------- fused q-up GEMM + attention epilogue ----------------
// Each block: QF tile = 256 tokens x 256 cols = 4 attention sub-problems
// (2 q-tiles x 2 heads). GEMM acc -> plain LDS; per-quarter (256 threads)
// runs the verified attn flow: LN+RoPE (plain->swizzled, in place), QK^T
// (K from global), softmax, P overlay, PV (V^T from global), ATT write.
__global__ __launch_bounds__(1024, 1) void qup_attn_k(
    const bf16* __restrict__ QMID, const bf16* __restrict__ WUQ,
    const bf16* __restrict__ kc, const bf16* __restrict__ vt,
    const float* __restrict__ sink_logits,
    const float* __restrict__ gamma, const float* __restrict__ beta,
    const float2* __restrict__ rope, bf16* __restrict__ out) {
  __shared__ __align__(16) char lds[131072];
  const int wgid = (blockIdx.x & 7) * 64 + (blockIdx.x >> 3);  // grid 512, bijective
  gemm8p_body<2>(lds, QMID, 768, WUQ, 512, nullptr, 0, 512, 8, wgid);
  __syncthreads();  // plain Q tiles complete in LDS

  const int mt = wgid >> 3, nt = wgid & 7;
  const int sub = threadIdx.x >> 8;   // 0..3: (token-half, head-half)
  const int lt = threadIdx.x & 255;
  const int lw = (threadIdx.x >> 6) & 3;  // wave within sub-problem
  const int lane = threadIdx.x & 63;
  const int l15 = lane & 15, g = lane >> 4;
  const int tglob0 = mt * 256 + (sub >> 1) * 128;
  const int b = tglob0 >> 13;
  const int qt = (tglob0 & 8191) >> 7;
  const int hh = nt * 2 + (sub & 1);
  const int nk = qt + 1;
  const int ntk = (nk + 15) >> 4;
  const int nkk = (nk + 31) >> 5;
  bf16* Qs = (bf16*)lds + sub * 16384;  // [128][128] plain now; swizzled after LN
  const bf16* kbase = kc + (size_t)b * 64 * 128;
  const bf16* vbase = vt + (size_t)b * 128 * 64;

  // ---- LN + partial RoPE: read own plain half-row, write back swizzled (disjoint ranges) ----
  {
    const int q = lt >> 1, hf = lt & 1;
    bf16x8 r[8];
#pragma unroll
    for (int i = 0; i < 8; i++) r[i] = *(const bf16x8*)(Qs + q * 128 + hf * 64 + i * 8);
    float sum = 0.f;
#pragma unroll
    for (int i = 0; i < 8; i++)
#pragma unroll
      for (int j = 0; j < 8; j++) sum += b2f(r[i][j]);
    sum += __shfl_xor(sum, 1);
    const float mu = sum * (1.f / 128.f);
    float var = 0.f;
#pragma unroll
    for (int i = 0; i < 8; i++)
#pragma unroll
      for (int j = 0; j < 8; j++) { float d = b2f(r[i][j]) - mu; var += d * d; }
    var += __shfl_xor(var, 1);
    const float inv = rsqrtf(var * (1.f / 128.f) + 1e-6f);
    const int c0 = hf * 64;
#pragma unroll
    for (int i = 0; i < 8; i++) {
      float y[8];
#pragma unroll
      for (int j = 0; j < 8; j++) {
        int ch = c0 + i * 8 + j;
        y[j] = (b2f(r[i][j]) - mu) * inv * gamma[ch] + beta[ch];
      }
      if (hf) {
#pragma unroll
        for (int j = 0; j < 8; j += 2) {
          float2 cs = rope[((size_t)qt * 128 + q) * 32 + i * 4 + (j >> 1)];
          float e = y[j], o = y[j + 1];
          y[j] = e * cs.x - o * cs.y;
          y[j + 1] = e * cs.y + o * cs.x;
        }
      }
      bf16x8 w;
#pragma unroll
      for (int j = 0; j < 8; j++) w[j] = f2bs(y[j]);
      *(bf16x8*)(Qs + q * 128 + ((hf * 8 + (i ^ (q & 7))) << 3)) = w;
    }
  }
  __syncthreads();

  bf16x8 af[2][4];
#pragma unroll
  for (int m = 0; m < 2; m++) {
    const int q = lw * 32 + m * 16 + l15;
#pragma unroll
    for (int kk = 0; kk < 4; kk++) {
      const int u = (kk * 4 + g) ^ (q & 7);
      af[m][kk] = *(const bf16x8*)(Qs + q * 128 + u * 8);
    }
  }
  __syncthreads();  // Qs dead; safe to overlay P

  f32x4 sacc[2][4] = {};
#pragma unroll
  for (int n = 0; n < 4; n++) {
    if (n < ntk) {
      const bf16* kr = kbase + (n * 16 + l15) * 128 + g * 8;
      bf16x8 b0 = *(const bf16x8*)(kr);
      bf16x8 b1 = *(const bf16x8*)(kr + 32);
      bf16x8 b2 = *(const bf16x8*)(kr + 64);
      bf16x8 b3 = *(const bf16x8*)(kr + 96);
      __builtin_amdgcn_s_setprio(1);
      sacc[0][n] = mfma16(af[0][0], b0, sacc[0][n]);
      sacc[1][n] = mfma16(af[1][0], b0, sacc[1][n]);
      sacc[0][n] = mfma16(af[0][1], b1, sacc[0][n]);
      sacc[1][n] = mfma16(af[1][1], b1, sacc[1][n]);
      sacc[0][n] = mfma16(af[0][2], b2, sacc[0][n]);
      sacc[1][n] = mfma16(af[1][2], b2, sacc[1][n]);
      sacc[0][n] = mfma16(af[0][3], b3, sacc[0][n]);
      sacc[1][n] = mfma16(af[1][3], b3, sacc[1][n]);
      __builtin_amdgcn_s_setprio(0);
    }
  }

  const float sink = expf(sink_logits[hh]);
  const float scale = 0.088388347648318447f;  // 1/sqrt(128)
  bf16* P = Qs;
#pragma unroll
  for (int m = 0; m < 2; m++) {
    float pv[4][4];
    float rs[4] = {0.f, 0.f, 0.f, 0.f};
#pragma unroll
    for (int n = 0; n < 4; n++) {
      int key = n * 16 + l15;
#pragma unroll
      for (int j = 0; j < 4; j++) {
        float p = (key < nk) ? expf(sacc[m][n][j] * scale) : 0.f;
        pv[n][j] = p;
        rs[j] += p;
      }
    }
#pragma unroll
    for (int j = 0; j < 4; j++) {
      float v = rs[j];
      v += __shfl_xor(v, 1); v += __shfl_xor(v, 2);
      v += __shfl_xor(v, 4); v += __shfl_xor(v, 8);
      rs[j] = 1.0f / (v + sink);
    }
    const int row0 = lw * 32 + m * 16 + (g << 2);
#pragma unroll
    for (int n = 0; n < 4; n++)
#pragma unroll
      for (int j = 0; j < 4; j++) {
        int q = row0 + j;
        int k = n * 16 + l15;
        P[q * 64 + ((((k >> 3) ^ (q & 7)) << 3) | (k & 7))] =
            __float2bfloat16(pv[n][j] * rs[j]);
      }
  }
  // no barrier: PV reads only this wave's own P rows

  f32x4 oacc[2][8] = {};
#pragma unroll
  for (int kk = 0; kk < 2; kk++) {
    if (kk < nkk) {
      bf16x8 pa[2];
#pragma unroll
      for (int m = 0; m < 2; m++) {
        const int q = lw * 32 + m * 16 + l15;
        const int u = (kk * 4 + g) ^ (q & 7);
        pa[m] = *(const bf16x8*)(P + q * 64 + u * 8);
      }
#pragma unroll
      for (int n = 0; n < 8; n++) {
        bf16x8 vb = *(const bf16x8*)(vbase + (n * 16 + l15) * 64 + kk * 32 + g * 8);
        __builtin_amdgcn_s_setprio(1);
        oacc[0][n] = mfma16(pa[0], vb, oacc[0][n]);
        oacc[1][n] = mfma16(pa[1], vb, oacc[1][n]);
        __builtin_amdgcn_s_setprio(0);
      }
    }
  }

  bf16* ob = out + ((size_t)b * 8192 + (size_t)qt * 128) * 2048 + hh * 128;
  const int r4 = g << 2;
#pragma unroll
  for (int m = 0; m < 2; m++)
#pragma unroll
    for (int n = 0; n < 8; n++)
#pragma unroll
      for (int j = 0; j < 4; j++)
        ob[(size_t)(lw * 32 + m * 16 + r4 + j) * 2048 + n * 16 + l15] =
            __float2bfloat16(oacc[m][n][j]);
}

extern "C" void kernel_launch(void* const* d_in, const int* in_sizes, int n_in,
                              void* d_out, int out_size, void* d_ws, size_t ws_size,
                              hipStream_t stream) {
  const float* x      = (const float*)d_in[0];
  const float* w_kv   = (const float*)d_in[1];
  const float* w_z    = (const float*)d_in[2];
  const float* b_comp = (const float*)d_in[3];
  const float* w_dq   = (const float*)d_in[4];
  const float* w_uq   = (const float*)d_in[5];
  const float* o_down = (const float*)d_in[6];
  const float* o_up   = (const float*)d_in[7];
  const float* kv_g   = (const float*)d_in[8];
  const float* kv_b   = (const float*)d_in[9];
  const float* q_g    = (const float*)d_in[10];
  const float* q_b    = (const float*)d_in[11];
  const float* sinkl  = (const float*)d_in[12];
  char* ws = (char*)d_ws;
  bf16*   WCZQ  = (bf16*)(ws + OFF_WCZQ);
  bf16*   WUQ   = (bf16*)(ws + OFF_WUQ);
  bf16*   DOWNB = (bf16*)(ws + OFF_DOWNB);
  bf16*   WUP   = (bf16*)(ws + OFF_WUP);
  bf16*   W2T   = (bf16*)(ws + OFF_W2T);
  bf16*   KC    = (bf16*)(ws + OFF_KC);
  bf16*   VT    = (bf16*)(ws + OFF_VT);
  float2* ROPE  = (float2*)(ws + OFF_ROPE);
  bf16*   XB    = (bf16*)(ws + OFF_XB);
  bf16*   CZQ   = (bf16*)(ws + OFF_CZQ);
  bf16*   ATT   = (bf16*)(ws + OFF_XB);
  float*  OUT   = (float*)d_out;

  // all weight prep + converts + rope table in one launch
  prep_k<<<24576, 256, 0, stream>>>(w_kv, w_z, w_dq, w_uq, o_up, o_down, x,
                                    WCZQ, WUQ, WUP, DOWNB, XB, ROPE);
  // czq GEMM + inline compression/kv-LN + W2T group GEMMs, one full-machine launch
  czq_w2t_k<<<256, 1024, 0, stream>>>(XB, WCZQ, CZQ, WUP, DOWNB, W2T,
                                      b_comp, kv_g, kv_b, KC, VT);
  // q-up GEMM (16384x2048, K=512) with fused q-LN + RoPE + attention
  qup_attn_k<<<512, 1024, 0, stream>>>(CZQ + 256, WUQ, KC, VT, sinkl,
                                       q_g, q_b, ROPE, ATT);
  // final: OUT = ATT @ W2T^T  (16384 x 2048, K=2048)
  gemm8p<0><<<512, 1024, 0, stream>>>(ATT, DM, W2T, DM, OUT, DM, DM, 8);
}